// Round 1
// baseline (596.465 us; speedup 1.0000x reference)
//
#include <hip/hip_runtime.h>
#include <math.h>

// ---------------------------------------------------------------------------
// PatientDistillation: three losses.
//  out[0] = train_loss (CE over s_logits/labels)
//  out[1] = soft_loss  (KL(batchmean) at temperature T, * T^2)
//  out[2] = distill_loss (sum over rows of k smallest same-label sq dists / D)
//
// Heavy part: dot[i][j] = sf_i . tf_j  (B x B x K GEMM, K = S*H = 98304)
// sq[i][j] = max(0, ||sf_i||^2 + ||tf_j||^2 - 2 dot[i][j])
// ---------------------------------------------------------------------------

#define GEMM_BM 64
#define GEMM_BN 64
#define GEMM_BK 16

// ---------------- norms: one block per row (2B blocks) ---------------------
__global__ __launch_bounds__(256) void norms_kernel(const float* __restrict__ S,
                                                    const float* __restrict__ T,
                                                    float* __restrict__ s_nrm,
                                                    float* __restrict__ t_nrm,
                                                    int B, int D) {
    const int r = blockIdx.x;
    const int tid = threadIdx.x;
    const float* src = (r < B) ? (S + (size_t)r * D) : (T + (size_t)(r - B) * D);

    float sum = 0.0f;
    const int nv = D >> 2;
    const float4* p = (const float4*)src;
    for (int idx = tid; idx < nv; idx += 256) {
        float4 v = p[idx];
        sum += v.x * v.x + v.y * v.y + v.z * v.z + v.w * v.w;
    }
    for (int idx = (nv << 2) + tid; idx < D; idx += 256) {
        float v = src[idx];
        sum += v * v;
    }
    // wave reduce (64-wide) then cross-wave via LDS
    #pragma unroll
    for (int off = 32; off > 0; off >>= 1) sum += __shfl_down(sum, off, 64);
    __shared__ float wsum[4];
    if ((tid & 63) == 0) wsum[tid >> 6] = sum;
    __syncthreads();
    if (tid == 0) {
        float total = wsum[0] + wsum[1] + wsum[2] + wsum[3];
        if (r < B) s_nrm[r] = total;
        else       t_nrm[r - B] = total;
    }
}

// ---------------- split-K f32 SGEMM: dot += S * T^T ------------------------
// grid: (B/64, B/64, K/KC). 256 threads, each computes a 4x4 micro-tile.
__global__ __launch_bounds__(256) void gemm_dot_kernel(const float* __restrict__ S,
                                                       const float* __restrict__ T,
                                                       float* __restrict__ dotb,
                                                       int B, int K, int KC) {
    __shared__ float As[GEMM_BK][GEMM_BM];
    __shared__ float Bs[GEMM_BK][GEMM_BN];
    const int tid = threadIdx.x;
    const int i0 = blockIdx.x * GEMM_BM;
    const int j0 = blockIdx.y * GEMM_BN;
    const int kbeg = blockIdx.z * KC;
    const int kend = (kbeg + KC < K) ? (kbeg + KC) : K;
    const int tx = tid & 15;   // col group (4 cols each)
    const int ty = tid >> 4;   // row group (4 rows each)

    float acc[4][4] = {};

    for (int kb = kbeg; kb < kend; kb += GEMM_BK) {
        // stage 64x16 tiles of S-rows (i0..) and T-rows (j0..); 4 elems/thread each
        #pragma unroll
        for (int l = 0; l < 4; ++l) {
            int idx = tid + l * 256;
            int m = idx >> 4;      // 0..63
            int kk = idx & 15;     // 0..15
            int gk = kb + kk;
            float av = 0.0f, bv = 0.0f;
            if (gk < K) {
                int gi = i0 + m;
                int gj = j0 + m;
                if (gi < B) av = S[(size_t)gi * K + gk];
                if (gj < B) bv = T[(size_t)gj * K + gk];
            }
            As[kk][m] = av;
            Bs[kk][m] = bv;
        }
        __syncthreads();
        #pragma unroll
        for (int kk = 0; kk < GEMM_BK; ++kk) {
            float4 a = *(const float4*)&As[kk][ty * 4];
            float4 b = *(const float4*)&Bs[kk][tx * 4];
            float av[4] = {a.x, a.y, a.z, a.w};
            float bw[4] = {b.x, b.y, b.z, b.w};
            #pragma unroll
            for (int r = 0; r < 4; ++r)
                #pragma unroll
                for (int c = 0; c < 4; ++c)
                    acc[r][c] += av[r] * bw[c];
        }
        __syncthreads();
    }

    #pragma unroll
    for (int r = 0; r < 4; ++r) {
        int gi = i0 + ty * 4 + r;
        if (gi >= B) continue;
        #pragma unroll
        for (int c = 0; c < 4; ++c) {
            int gj = j0 + tx * 4 + c;
            if (gj < B) atomicAdd(&dotb[(size_t)gi * B + gj], acc[r][c]);
        }
    }
}

// ---------------- per-row masked top-k smallest ----------------------------
// one block (256 threads) per row i; B <= 256 assumed.
__global__ __launch_bounds__(256) void topk_kernel(const float* __restrict__ dotb,
                                                   const float* __restrict__ s_nrm,
                                                   const float* __restrict__ t_nrm,
                                                   const int* __restrict__ labels,
                                                   const int* __restrict__ kp,
                                                   float* __restrict__ accum,
                                                   int B) {
    const int i = blockIdx.x;
    const int tid = threadIdx.x;
    __shared__ float svals[256];
    __shared__ float rv[256];
    __shared__ int   ri[256];

    float v = INFINITY;
    if (tid < B && labels[i] == labels[tid]) {
        float d = s_nrm[i] + t_nrm[tid] - 2.0f * dotb[(size_t)i * B + tid];
        v = fmaxf(d, 0.0f);
    }
    svals[tid] = v;
    __syncthreads();

    const int k = kp[0];
    float sum = 0.0f;
    for (int it = 0; it < k; ++it) {
        rv[tid] = svals[tid];
        ri[tid] = tid;
        __syncthreads();
        #pragma unroll
        for (int s = 128; s > 0; s >>= 1) {
            if (tid < s) {
                if (rv[tid + s] < rv[tid]) { rv[tid] = rv[tid + s]; ri[tid] = ri[tid + s]; }
            }
            __syncthreads();
        }
        if (tid == 0) {
            float mv = rv[0];
            if (mv < 3.0e38f) sum += mv;   // isfinite guard (groups < k)
            svals[ri[0]] = INFINITY;       // exclude for next iteration
        }
        __syncthreads();
    }
    if (tid == 0) atomicAdd(accum, sum);
}

// ---------------- finalize: CE + KL + scale distill ------------------------
__global__ __launch_bounds__(256) void finalize_kernel(const float* __restrict__ t_logits,
                                                       const float* __restrict__ s_logits,
                                                       const int* __restrict__ labels,
                                                       const int* __restrict__ tp,
                                                       const float* __restrict__ accum,
                                                       float* __restrict__ out,
                                                       int B, int NL, int D) {
    const int tid = threadIdx.x;
    const float Tv = (float)tp[0];
    float ce = 0.0f, kl = 0.0f;

    for (int i = tid; i < B; i += 256) {
        const float* sl = s_logits + (size_t)i * NL;
        const float* tl = t_logits + (size_t)i * NL;
        // cross-entropy on raw student logits
        float mx = -INFINITY;
        for (int c = 0; c < NL; ++c) mx = fmaxf(mx, sl[c]);
        float se = 0.0f;
        for (int c = 0; c < NL; ++c) se += expf(sl[c] - mx);
        float lse = logf(se) + mx;
        ce += lse - sl[labels[i]];
        // KL at temperature
        float mxs = -INFINITY, mxt = -INFINITY;
        for (int c = 0; c < NL; ++c) {
            mxs = fmaxf(mxs, sl[c] / Tv);
            mxt = fmaxf(mxt, tl[c] / Tv);
        }
        float ses = 0.0f, set = 0.0f;
        for (int c = 0; c < NL; ++c) {
            ses += expf(sl[c] / Tv - mxs);
            set += expf(tl[c] / Tv - mxt);
        }
        float lses = logf(ses) + mxs;
        float lset = logf(set) + mxt;
        for (int c = 0; c < NL; ++c) {
            float lst = tl[c] / Tv - lset;   // log soft target
            float ls  = sl[c] / Tv - lses;   // student log prob
            kl += expf(lst) * (lst - ls);
        }
    }

    // block reduce ce and kl
    #pragma unroll
    for (int off = 32; off > 0; off >>= 1) {
        ce += __shfl_down(ce, off, 64);
        kl += __shfl_down(kl, off, 64);
    }
    __shared__ float wce[4], wkl[4];
    if ((tid & 63) == 0) { wce[tid >> 6] = ce; wkl[tid >> 6] = kl; }
    __syncthreads();
    if (tid == 0) {
        float ce_t = wce[0] + wce[1] + wce[2] + wce[3];
        float kl_t = wkl[0] + wkl[1] + wkl[2] + wkl[3];
        out[0] = ce_t / (float)B;
        out[1] = kl_t / (float)B * Tv * Tv;
        out[2] = accum[0] / (float)D;
    }
}

// ---------------------------------------------------------------------------
extern "C" void kernel_launch(void* const* d_in, const int* in_sizes, int n_in,
                              void* d_out, int out_size, void* d_ws, size_t ws_size,
                              hipStream_t stream) {
    const float* t_logits = (const float*)d_in[0];
    const float* s_logits = (const float*)d_in[1];
    const float* t_feat   = (const float*)d_in[2];
    const float* s_feat   = (const float*)d_in[3];
    const int*   labels   = (const int*)d_in[4];
    const int*   kp       = (const int*)d_in[5];
    const int*   tp       = (const int*)d_in[6];
    float* out = (float*)d_out;

    const int B  = in_sizes[4];          // 256
    const int NL = in_sizes[0] / B;      // 2
    const int D  = in_sizes[2] / B;      // S*H = 98304

    float* ws      = (float*)d_ws;
    float* dotb    = ws;                 // B*B
    float* s_nrm   = ws + (size_t)B * B; // B
    float* t_nrm   = s_nrm + B;          // B
    float* accum   = t_nrm + B;          // 1

    hipMemsetAsync(d_ws, 0, sizeof(float) * ((size_t)B * B + 2 * B + 1), stream);

    // row norms for both feature matrices
    norms_kernel<<<2 * B, 256, 0, stream>>>(s_feat, t_feat, s_nrm, t_nrm, B, D);

    // split-K GEMM: pick gz so each chunk is a multiple of GEMM_BK
    int gz = 1;
    const int cands[] = {48, 64, 32, 24, 16, 12, 8, 6, 4, 3, 2};
    for (int ci = 0; ci < 11; ++ci) {
        if (D % (cands[ci] * GEMM_BK) == 0) { gz = cands[ci]; break; }
    }
    int KC = D / gz;
    dim3 grid((B + GEMM_BM - 1) / GEMM_BM, (B + GEMM_BN - 1) / GEMM_BN, gz);
    gemm_dot_kernel<<<grid, 256, 0, stream>>>(s_feat, t_feat, dotb, B, D, KC);

    // per-row top-k smallest same-label distances
    topk_kernel<<<B, 256, 0, stream>>>(dotb, s_nrm, t_nrm, labels, kp, accum, B);

    // cheap losses + final scaling
    finalize_kernel<<<1, 256, 0, stream>>>(t_logits, s_logits, labels, tp, accum,
                                           out, B, NL, D);
}